// Round 1
// baseline (515.778 us; speedup 1.0000x reference)
//
#include <hip/hip_runtime.h>
#include <stdint.h>

#define GAS __attribute__((address_space(1)))
#define LAS __attribute__((address_space(3)))

typedef __attribute__((ext_vector_type(8))) __bf16 bf16x8;
typedef __attribute__((ext_vector_type(4))) float f32x4;

static constexpr int Bb = 4, Ll = 2048, Dd = 512, Hh = 8, DHd = 64;

__device__ __forceinline__ unsigned short f2bf(float f){
  unsigned u = __float_as_uint(f);
  u += 0x7fffu + ((u >> 16) & 1u);           // round-to-nearest-even
  return (unsigned short)(u >> 16);
}
__device__ __forceinline__ float bf2f(unsigned short s){
  return __uint_as_float(((unsigned)s) << 16);
}
__device__ __forceinline__ void gload16(const void* g, void* l){
  __builtin_amdgcn_global_load_lds((const GAS void*)g, (LAS void*)l, 16, 0, 0);
}
__device__ __forceinline__ f32x4 mfma16(bf16x8 a, bf16x8 b, f32x4 c){
  return __builtin_amdgcn_mfma_f32_16x16x32_bf16(a, b, c, 0, 0, 0);
}

// ---------------------------------------------------------------------------
// row sum-of-squares + f32 -> bf16 cast.  grid = B*L, block = 256 (2 elems/thr)
__global__ __launch_bounds__(256) void sumsq_cast(const float* __restrict__ x,
                                                  unsigned short* __restrict__ xbf,
                                                  float* __restrict__ sq){
  int row = blockIdx.x, tid = threadIdx.x;
  float2 v = ((const float2*)(x + (size_t)row * Dd))[tid];
  ((unsigned*)(xbf + (size_t)row * Dd))[tid] =
      (unsigned)f2bf(v.x) | ((unsigned)f2bf(v.y) << 16);
  float s2 = v.x * v.x + v.y * v.y;
  #pragma unroll
  for (int t = 1; t < 64; t <<= 1) s2 += __shfl_xor(s2, t, 64);
  __shared__ float red[4];
  if ((tid & 63) == 0) red[tid >> 6] = s2;
  __syncthreads();
  if (tid == 0) sq[row] = red[0] + red[1] + red[2] + red[3];
}

// ---------------------------------------------------------------------------
// f32 (R,C) -> bf16 (C,R) transpose.  block (32,8), grid (C/32, R/32)
__global__ void transpose_w(const float* __restrict__ in, unsigned short* __restrict__ out,
                            int R, int C){
  __shared__ float t[32][33];
  int tx = threadIdx.x, ty = threadIdx.y;
  int c0 = blockIdx.x * 32, r0 = blockIdx.y * 32;
  #pragma unroll
  for (int j = 0; j < 32; j += 8) t[ty + j][tx] = in[(size_t)(r0 + ty + j) * C + c0 + tx];
  __syncthreads();
  #pragma unroll
  for (int j = 0; j < 32; j += 8) out[(size_t)(c0 + ty + j) * R + r0 + tx] = f2bf(t[tx][ty + j]);
}

// ---------------------------------------------------------------------------
// v (b,l,h,dh) bf16 -> vT (b,h,dh,l) bf16.  grid (L/64, H, B), block 256
__global__ __launch_bounds__(256) void v_transpose(const unsigned short* __restrict__ v,
                                                   unsigned short* __restrict__ vT){
  int b = blockIdx.z, h = blockIdx.y, l0 = blockIdx.x * 64;
  int tid = threadIdx.x;
  __shared__ unsigned short t[64 * 64];
  #pragma unroll
  for (int it = 0; it < 2; ++it){
    int row = tid >> 2;                 // local l
    int c = (tid & 3) + it * 4;         // 16B granule (8 dh)
    uint4 d = *(const uint4*)(v + (size_t)(b * Ll + l0 + row) * Dd + h * DHd + c * 8);
    *(uint4*)((char*)t + row * 128 + ((c ^ (row & 7)) << 4)) = d;
  }
  __syncthreads();
  #pragma unroll
  for (int it = 0; it < 2; ++it){
    int dh = tid >> 2;
    int c2 = (tid & 3) + it * 4;        // granule along l (8 l-values)
    unsigned pk[4];
    #pragma unroll
    for (int p = 0; p < 4; ++p){
      unsigned short e0, e1;
      {
        int ll = c2 * 8 + p * 2;
        e0 = *(const unsigned short*)((const char*)t + ll * 128 +
              ((((dh >> 3) ^ (ll & 7))) << 4) + ((dh & 7) << 1));
        ll = c2 * 8 + p * 2 + 1;
        e1 = *(const unsigned short*)((const char*)t + ll * 128 +
              ((((dh >> 3) ^ (ll & 7))) << 4) + ((dh & 7) << 1));
      }
      pk[p] = (unsigned)e0 | ((unsigned)e1 << 16);
    }
    uint4 o; o.x = pk[0]; o.y = pk[1]; o.z = pk[2]; o.w = pk[3];
    *(uint4*)(vT + ((size_t)(b * Hh + h) * DHd + dh) * Ll + l0 + c2 * 8) = o;
  }
}

// ---------------------------------------------------------------------------
// generic 128x128x64 bf16 MFMA GEMM, B given transposed (N,K) row-major.
// MODE 0: gram/cdist epilogue (batched via blockIdx.z)
// MODE 1: +bias -> bf16          MODE 3: relu(+bias) -> bf16
// MODE 2/4: +bias +extra -> f32
template<int MODE>
__global__ __launch_bounds__(256) void gemm_bt(
    const unsigned short* __restrict__ A,
    const unsigned short* __restrict__ Bt,
    int M, int N, int K,
    const float* __restrict__ bias,
    const float* __restrict__ extra,
    float* __restrict__ outf,
    unsigned short* __restrict__ outb,
    const float* __restrict__ sq,
    float* __restrict__ rmax,
    const float* __restrict__ mask)
{
  if (MODE == 0){
    int z = blockIdx.z;
    A    += (size_t)z * Ll * Dd;
    Bt    = A;
    outb += (size_t)z * Ll * Ll;
    sq += z * Ll; rmax += z * Ll; mask += z * Ll;
  }
  const int m0 = blockIdx.y * 128, n0 = blockIdx.x * 128;
  const int tid = threadIdx.x, w = tid >> 6, l = tid & 63;
  const int wm = w >> 1, wn = w & 1;
  __shared__ unsigned short lA[128 * 64];
  __shared__ unsigned short lB[128 * 64];
  f32x4 acc[4][4];
  const f32x4 z4 = {0.f, 0.f, 0.f, 0.f};
  #pragma unroll
  for (int i = 0; i < 4; i++){
    #pragma unroll
    for (int j = 0; j < 4; j++) acc[i][j] = z4;
  }
  const int srow = w * 8 + (l >> 3);
  const int sc = l & 7;

  for (int k0 = 0; k0 < K; k0 += 64){
    #pragma unroll
    for (int j = 0; j < 4; j++){
      int row = j * 32 + srow;
      gload16(A + (size_t)(m0 + row) * K + k0 + ((sc ^ (row & 7)) << 3),
              lA + j * 2048 + w * 512);
    }
    #pragma unroll
    for (int j = 0; j < 4; j++){
      int row = j * 32 + srow;
      gload16(Bt + (size_t)(n0 + row) * K + k0 + ((sc ^ (row & 7)) << 3),
              lB + j * 2048 + w * 512);
    }
    __syncthreads();
    bf16x8 af[4][2], bv[4][2];
    #pragma unroll
    for (int kk = 0; kk < 2; kk++){
      #pragma unroll
      for (int f = 0; f < 4; f++){
        int ra = wm * 64 + f * 16 + (l & 15);
        af[f][kk] = *(const bf16x8*)((const char*)lA + ra * 128 +
                      (((kk * 4 + (l >> 4)) ^ (ra & 7)) << 4));
        int rb = wn * 64 + f * 16 + (l & 15);
        bv[f][kk] = *(const bf16x8*)((const char*)lB + rb * 128 +
                      (((kk * 4 + (l >> 4)) ^ (rb & 7)) << 4));
      }
    }
    #pragma unroll
    for (int mf = 0; mf < 4; mf++){
      #pragma unroll
      for (int nf = 0; nf < 4; nf++){
        #pragma unroll
        for (int kk = 0; kk < 2; kk++)
          acc[mf][nf] = mfma16(af[mf][kk], bv[nf][kk], acc[mf][nf]);
      }
    }
    __syncthreads();
  }

  #pragma unroll
  for (int mf = 0; mf < 4; mf++){
    #pragma unroll
    for (int r = 0; r < 4; r++){
      int row = m0 + wm * 64 + mf * 16 + (l >> 4) * 4 + r;
      if (MODE == 0){
        float sqi = sq[row];
        float mi  = mask[row];
        float rm = 0.f;
        #pragma unroll
        for (int nf = 0; nf < 4; nf++){
          int col = n0 + wn * 64 + nf * 16 + (l & 15);
          float g  = acc[mf][nf][r];
          float d2 = sqi + sq[col] - 2.f * g;
          float cd = sqrtf(fmaxf(d2, 0.f));
          float cdm = cd * (mi * mask[col]);
          outb[(size_t)row * Ll + col] = f2bf(cdm);
          rm = fmaxf(rm, cdm);
        }
        #pragma unroll
        for (int t = 1; t < 16; t <<= 1) rm = fmaxf(rm, __shfl_xor(rm, t, 64));
        if ((l & 15) == 0) atomicMax((int*)(rmax + row), __float_as_int(rm));
      } else {
        #pragma unroll
        for (int nf = 0; nf < 4; nf++){
          int col = n0 + wn * 64 + nf * 16 + (l & 15);
          float v = acc[mf][nf][r] + bias[col];
          if (MODE == 1) outb[(size_t)row * N + col] = f2bf(v);
          if (MODE == 3) outb[(size_t)row * N + col] = f2bf(fmaxf(v, 0.f));
          if (MODE == 2 || MODE == 4)
            outf[(size_t)row * N + col] = v + extra[(size_t)row * N + col];
        }
      }
    }
  }
}

// ---------------------------------------------------------------------------
// flash attention with distance-residual bias.
// grid (L/64, H, B), block 256 (4 waves x 16 q-rows).  KBLK = 64.
__global__ __launch_bounds__(256) void flash_attn(
    const unsigned short* __restrict__ q,
    const unsigned short* __restrict__ k,
    const unsigned short* __restrict__ vT,
    const unsigned short* __restrict__ cdm,
    const float* __restrict__ rmax,
    const float* __restrict__ mask,
    unsigned short* __restrict__ y)
{
  int b = blockIdx.z, h = blockIdx.y, q0 = blockIdx.x * 64;
  int tid = threadIdx.x, w = tid >> 6, l = tid & 63;
  __shared__ unsigned short Qs[64 * 64];
  __shared__ unsigned short Ks[64 * 64];
  __shared__ unsigned short Vs[64 * 64];
  __shared__ unsigned short Ps[4 * 16 * 64];

  const int srow = w * 8 + (l >> 3);
  const int sc = l & 7;
  #pragma unroll
  for (int j = 0; j < 2; j++){
    int row = j * 32 + srow;
    gload16(q + (size_t)(b * Ll + q0 + row) * Dd + h * DHd + ((sc ^ (row & 7)) << 3),
            Qs + j * 2048 + w * 512);
  }

  f32x4 o[4];
  const f32x4 z4 = {0.f, 0.f, 0.f, 0.f};
  #pragma unroll
  for (int nf = 0; nf < 4; nf++) o[nf] = z4;
  float mprev[4], lsum[4], rmx[4], mq[4];
  #pragma unroll
  for (int r = 0; r < 4; r++){
    int qg = q0 + w * 16 + (l >> 4) * 4 + r;
    mprev[r] = -1e30f; lsum[r] = 0.f;
    rmx[r] = rmax[b * Ll + qg];
    mq[r]  = mask[b * Ll + qg];
  }

  for (int k0 = 0; k0 < Ll; k0 += 64){
    #pragma unroll
    for (int j = 0; j < 2; j++){
      int row = j * 32 + srow;
      gload16(k + (size_t)(b * Ll + k0 + row) * Dd + h * DHd + ((sc ^ (row & 7)) << 3),
              Ks + j * 2048 + w * 512);
      gload16(vT + ((size_t)(b * Hh + h) * DHd + row) * Ll + k0 + ((sc ^ (row & 7)) << 3),
              Vs + j * 2048 + w * 512);
    }
    __syncthreads();

    // S = Q K^T
    bf16x8 qa[2];
    #pragma unroll
    for (int kk = 0; kk < 2; kk++){
      int ra = w * 16 + (l & 15);
      qa[kk] = *(const bf16x8*)((const char*)Qs + ra * 128 +
                 (((kk * 4 + (l >> 4)) ^ (ra & 7)) << 4));
    }
    f32x4 s[4];
    #pragma unroll
    for (int nf = 0; nf < 4; nf++){
      s[nf] = z4;
      #pragma unroll
      for (int kk = 0; kk < 2; kk++){
        int rb = nf * 16 + (l & 15);
        bf16x8 kb = *(const bf16x8*)((const char*)Ks + rb * 128 +
                      (((kk * 4 + (l >> 4)) ^ (rb & 7)) << 4));
        s[nf] = mfma16(qa[kk], kb, s[nf]);
      }
    }

    float mk[4];
    #pragma unroll
    for (int nf = 0; nf < 4; nf++) mk[nf] = mask[b * Ll + k0 + nf * 16 + (l & 15)];

    float al[4];
    #pragma unroll
    for (int r = 0; r < 4; r++){
      int qg = q0 + w * 16 + (l >> 4) * 4 + r;
      float sv[4];
      #pragma unroll
      for (int nf = 0; nf < 4; nf++){
        int kg = k0 + nf * 16 + (l & 15);
        float cdv = bf2f(cdm[(size_t)(b * Ll + qg) * Ll + kg]);
        float bia = (qg != kg && (mq[r] * mk[nf]) != 0.f) ? (rmx[r] - cdv) : 0.f;
        sv[nf] = s[nf][r] * 0.125f + bia;
      }
      float tm = fmaxf(fmaxf(sv[0], sv[1]), fmaxf(sv[2], sv[3]));
      #pragma unroll
      for (int t = 1; t < 16; t <<= 1) tm = fmaxf(tm, __shfl_xor(tm, t, 64));
      float mnew = fmaxf(mprev[r], tm);
      float a_ = __expf(mprev[r] - mnew);
      float ps = 0.f;
      int rl = (l >> 4) * 4 + r;
      #pragma unroll
      for (int nf = 0; nf < 4; nf++){
        float p = __expf(sv[nf] - mnew);
        ps += p;
        int col = nf * 16 + (l & 15);
        *(unsigned short*)((char*)Ps + w * 2048 + rl * 128 +
            ((((col >> 3) ^ (rl & 7))) << 4) + ((col & 7) << 1)) = f2bf(p);
      }
      #pragma unroll
      for (int t = 1; t < 16; t <<= 1) ps += __shfl_xor(ps, t, 64);
      lsum[r] = lsum[r] * a_ + ps;
      mprev[r] = mnew;
      al[r] = a_;
    }

    #pragma unroll
    for (int nf = 0; nf < 4; nf++){
      f32x4 t = o[nf];
      t[0] *= al[0]; t[1] *= al[1]; t[2] *= al[2]; t[3] *= al[3];
      o[nf] = t;
    }

    bf16x8 pa[2];
    #pragma unroll
    for (int kk = 0; kk < 2; kk++){
      int rp = l & 15;
      pa[kk] = *(const bf16x8*)((const char*)Ps + w * 2048 + rp * 128 +
                 (((kk * 4 + (l >> 4)) ^ (rp & 7)) << 4));
    }
    #pragma unroll
    for (int nf = 0; nf < 4; nf++){
      #pragma unroll
      for (int kk = 0; kk < 2; kk++){
        int rv = nf * 16 + (l & 15);
        bf16x8 vb = *(const bf16x8*)((const char*)Vs + rv * 128 +
                      (((kk * 4 + (l >> 4)) ^ (rv & 7)) << 4));
        o[nf] = mfma16(pa[kk], vb, o[nf]);
      }
    }
    __syncthreads();
  }

  #pragma unroll
  for (int nf = 0; nf < 4; nf++){
    #pragma unroll
    for (int r = 0; r < 4; r++){
      int qg = q0 + w * 16 + (l >> 4) * 4 + r;
      float v = o[nf][r] / lsum[r];
      y[(size_t)(b * Ll + qg) * Dd + h * DHd + nf * 16 + (l & 15)] = f2bf(v);
    }
  }
}

// ---------------------------------------------------------------------------
// layernorm over D=512.  grid = B*L, block 256 (2 elems/thr)
__global__ __launch_bounds__(256) void ln_kernel(const float* __restrict__ in,
                                                 const float* __restrict__ g,
                                                 const float* __restrict__ bt,
                                                 float* __restrict__ outf,
                                                 unsigned short* __restrict__ outb){
  int row = blockIdx.x, tid = threadIdx.x;
  float2 v = ((const float2*)(in + (size_t)row * Dd))[tid];
  float s = v.x + v.y, s2 = v.x * v.x + v.y * v.y;
  #pragma unroll
  for (int t = 1; t < 64; t <<= 1){ s += __shfl_xor(s, t, 64); s2 += __shfl_xor(s2, t, 64); }
  __shared__ float red[8];
  if ((tid & 63) == 0){ red[tid >> 6] = s; red[4 + (tid >> 6)] = s2; }
  __syncthreads();
  float S  = red[0] + red[1] + red[2] + red[3];
  float S2 = red[4] + red[5] + red[6] + red[7];
  float mu = S * (1.f / 512.f);
  float var = fmaxf(S2 * (1.f / 512.f) - mu * mu, 0.f);
  float rs = rsqrtf(var + 1e-5f);
  int c = tid * 2;
  float o0 = (v.x - mu) * rs * g[c] + bt[c];
  float o1 = (v.y - mu) * rs * g[c + 1] + bt[c + 1];
  float2 ov; ov.x = o0; ov.y = o1;
  ((float2*)(outf + (size_t)row * Dd))[tid] = ov;
  if (outb){
    ((unsigned*)(outb + (size_t)row * Dd))[tid] =
        (unsigned)f2bf(o0) | ((unsigned)f2bf(o1) << 16);
  }
}

// ---------------------------------------------------------------------------
extern "C" void kernel_launch(void* const* d_in, const int* in_sizes, int n_in,
                              void* d_out, int out_size, void* d_ws, size_t ws_size,
                              hipStream_t stream){
  const float* x     = (const float*)d_in[0];
  const float* nmask = (const float*)d_in[1];
  const float* wq = (const float*)d_in[2];  const float* bq = (const float*)d_in[3];
  const float* wk = (const float*)d_in[4];  const float* bk = (const float*)d_in[5];
  const float* wv = (const float*)d_in[6];  const float* bv = (const float*)d_in[7];
  const float* wo = (const float*)d_in[8];  const float* bo = (const float*)d_in[9];
  const float* ln1g = (const float*)d_in[10]; const float* ln1b = (const float*)d_in[11];
  const float* w1 = (const float*)d_in[12]; const float* b1 = (const float*)d_in[13];
  const float* w2 = (const float*)d_in[14]; const float* b2 = (const float*)d_in[15];
  const float* ln2g = (const float*)d_in[16]; const float* ln2b = (const float*)d_in[17];
  float* outp = (float*)d_out;
  char* ws = (char*)d_ws;

  // workspace layout (bytes)
  unsigned short* xbf = (unsigned short*)(ws + 0);            //  8 MB
  float* sq   = (float*)(ws + 8388608);                       //  32 KB
  float* rmax = (float*)(ws + 8421376);                       //  32 KB
  unsigned short* wqT = (unsigned short*)(ws + 8454144);      //  512 KB
  unsigned short* wkT = (unsigned short*)(ws + 8978432);
  unsigned short* wvT = (unsigned short*)(ws + 9502720);
  unsigned short* woT = (unsigned short*)(ws + 10027008);
  unsigned short* w1T = (unsigned short*)(ws + 10551296);     //  2 MB
  unsigned short* w2T = (unsigned short*)(ws + 12648448);     //  2 MB
  unsigned short* cdm = (unsigned short*)(ws + 14745600);     // 32 MB (later reused as h1)
  unsigned short* qb  = (unsigned short*)(ws + 48300032);     //  8 MB (later reused as Xbf)
  unsigned short* kb_ = (unsigned short*)(ws + 56688640);     //  8 MB
  unsigned short* vb_ = (unsigned short*)(ws + 65077248);     //  8 MB
  unsigned short* vT  = (unsigned short*)(ws + 73465856);     //  8 MB
  unsigned short* yb  = (unsigned short*)(ws + 81854464);     //  8 MB
  float* res = (float*)(ws + 90243072);                       // 16 MB (resid1, then resid2)
  float* Xf  = (float*)(ws + 107020288);                      // 16 MB
  unsigned short* h1  = cdm;   // reuse (cdist dead after attention)
  unsigned short* Xbf = qb;    // reuse (q dead after attention)

  hipMemsetAsync(rmax, 0, sizeof(float) * Bb * Ll, stream);

  sumsq_cast<<<Bb * Ll, 256, 0, stream>>>(x, xbf, sq);

  dim3 tb(32, 8);
  transpose_w<<<dim3(16, 16), tb, 0, stream>>>(wq, wqT, 512, 512);
  transpose_w<<<dim3(16, 16), tb, 0, stream>>>(wk, wkT, 512, 512);
  transpose_w<<<dim3(16, 16), tb, 0, stream>>>(wv, wvT, 512, 512);
  transpose_w<<<dim3(16, 16), tb, 0, stream>>>(wo, woT, 512, 512);
  transpose_w<<<dim3(64, 16), tb, 0, stream>>>(w1, w1T, 512, 2048);
  transpose_w<<<dim3(16, 64), tb, 0, stream>>>(w2, w2T, 2048, 512);

  // cdist: Gram + epilogue -> cdm (bf16), rmax
  gemm_bt<0><<<dim3(16, 16, 4), 256, 0, stream>>>(xbf, xbf, Ll, Ll, Dd,
      nullptr, nullptr, nullptr, cdm, sq, rmax, nmask);

  // QKV projections (natural (b,l,d) bf16)
  gemm_bt<1><<<dim3(4, 64, 1), 256, 0, stream>>>(xbf, wqT, Bb * Ll, Dd, Dd,
      bq, nullptr, nullptr, qb, nullptr, nullptr, nullptr);
  gemm_bt<1><<<dim3(4, 64, 1), 256, 0, stream>>>(xbf, wkT, Bb * Ll, Dd, Dd,
      bk, nullptr, nullptr, kb_, nullptr, nullptr, nullptr);
  gemm_bt<1><<<dim3(4, 64, 1), 256, 0, stream>>>(xbf, wvT, Bb * Ll, Dd, Dd,
      bv, nullptr, nullptr, vb_, nullptr, nullptr, nullptr);

  v_transpose<<<dim3(Ll / 64, Hh, Bb), 256, 0, stream>>>(vb_, vT);

  flash_attn<<<dim3(Ll / 64, Hh, Bb), 256, 0, stream>>>(qb, kb_, vT, cdm, rmax, nmask, yb);

  // out projection + residual -> resid1 (f32)
  gemm_bt<2><<<dim3(4, 64, 1), 256, 0, stream>>>(yb, woT, Bb * Ll, Dd, Dd,
      bo, x, res, nullptr, nullptr, nullptr, nullptr);

  ln_kernel<<<Bb * Ll, 256, 0, stream>>>(res, ln1g, ln1b, Xf, Xbf);

  // FFN
  gemm_bt<3><<<dim3(16, 64, 1), 256, 0, stream>>>(Xbf, w1T, Bb * Ll, 4 * Dd, Dd,
      b1, nullptr, nullptr, h1, nullptr, nullptr, nullptr);
  gemm_bt<4><<<dim3(4, 64, 1), 256, 0, stream>>>(h1, w2T, Bb * Ll, Dd, 4 * Dd,
      b2, Xf, res, nullptr, nullptr, nullptr, nullptr);

  ln_kernel<<<Bb * Ll, 256, 0, stream>>>(res, ln2g, ln2b, outp, nullptr);
}